// Round 9
// baseline (320.305 us; speedup 1.0000x reference)
//
#include <hip/hip_runtime.h>

typedef unsigned short u16;
typedef __attribute__((ext_vector_type(8))) short short8;
typedef __attribute__((ext_vector_type(4))) float f32x4;
typedef __attribute__((ext_vector_type(4))) unsigned int uint4v;
typedef __attribute__((ext_vector_type(4))) unsigned short ushort4v;

#define N_PIX 1024
constexpr float SCALE = 0.17677669529663687f;   // 32^-0.5
constexpr float QSC   = 0.25506626725324577f;   // SCALE * log2(e)

__device__ __forceinline__ float bf2f(u16 v) {
    unsigned u = ((unsigned)v) << 16;
    return __builtin_bit_cast(float, u);
}
__device__ __forceinline__ u16 f2bf(float f) {
    unsigned u = __builtin_bit_cast(unsigned, f);
    u += 0x7fff + ((u >> 16) & 1);
    return (u16)(u >> 16);
}
__device__ __forceinline__ float silu_f(float x) { return x / (1.f + __expf(-x)); }

__device__ __forceinline__ float exp2_f(float x) {
    float r; asm("v_exp_f32 %0, %1" : "=v"(r) : "v"(x)); return r;
}

__device__ __forceinline__ f32x4 mfma16(short8 a, short8 b, f32x4 c) {
    return __builtin_amdgcn_mfma_f32_16x16x32_bf16(a, b, c, 0, 0, 0);
}

__device__ __forceinline__ void gl_lds16(const u16* g, u16* l) {
    __builtin_amdgcn_global_load_lds(
        (const __attribute__((address_space(1))) unsigned int*)g,
        (__attribute__((address_space(3))) unsigned int*)l, 16, 0, 0);
}

// 16-lane (DPP-row) max reduce: xor1, xor2, xor7(=4 after quads), xor15(=8)
__device__ __forceinline__ float dpp_max16(float x) {
    int v = __builtin_bit_cast(int, x);
    x = fmaxf(x, __builtin_bit_cast(float, __builtin_amdgcn_mov_dpp(v, 0xB1, 0xF, 0xF, true)));
    v = __builtin_bit_cast(int, x);
    x = fmaxf(x, __builtin_bit_cast(float, __builtin_amdgcn_mov_dpp(v, 0x4E, 0xF, 0xF, true)));
    v = __builtin_bit_cast(int, x);
    x = fmaxf(x, __builtin_bit_cast(float, __builtin_amdgcn_mov_dpp(v, 0x141, 0xF, 0xF, true)));
    v = __builtin_bit_cast(int, x);
    x = fmaxf(x, __builtin_bit_cast(float, __builtin_amdgcn_mov_dpp(v, 0x140, 0xF, 0xF, true)));
    return x;
}
__device__ __forceinline__ float dpp_sum16(float x) {
    int v = __builtin_bit_cast(int, x);
    x += __builtin_bit_cast(float, __builtin_amdgcn_mov_dpp(v, 0xB1, 0xF, 0xF, true));
    v = __builtin_bit_cast(int, x);
    x += __builtin_bit_cast(float, __builtin_amdgcn_mov_dpp(v, 0x4E, 0xF, 0xF, true));
    v = __builtin_bit_cast(int, x);
    x += __builtin_bit_cast(float, __builtin_amdgcn_mov_dpp(v, 0x141, 0xF, 0xF, true));
    v = __builtin_bit_cast(int, x);
    x += __builtin_bit_cast(float, __builtin_amdgcn_mov_dpp(v, 0x140, 0xF, 0xF, true));
    return x;
}

// ---------------------------------------------------------------------------
// Weight fp32 -> bf16 conversion (6 segments, blockIdx.y selects)
// ---------------------------------------------------------------------------
__global__ void cvtw_k(const float* s0, u16* d0, int n0,
                       const float* s1, u16* d1, int n1,
                       const float* s2, u16* d2, int n2,
                       const float* s3, u16* d3, int n3,
                       const float* s4, u16* d4, int n4,
                       const float* s5, u16* d5, int n5)
{
    const float* sp = nullptr; u16* dp = nullptr; int n = 0;
    switch (blockIdx.y) {
        case 0: sp = s0; dp = d0; n = n0; break;
        case 1: sp = s1; dp = d1; n = n1; break;
        case 2: sp = s2; dp = d2; n = n2; break;
        case 3: sp = s3; dp = d3; n = n3; break;
        case 4: sp = s4; dp = d4; n = n4; break;
        case 5: sp = s5; dp = d5; n = n5; break;
    }
    for (int i = blockIdx.x * 256 + threadIdx.x; i < n; i += gridDim.x * 256)
        dp[i] = f2bf(sp[i]);
}

// ---------------------------------------------------------------------------
// x (b, 512, 1024) fp32 -> x_t (b, 1024, 512) bf16  (LDS-tiled transpose)
// ---------------------------------------------------------------------------
__global__ __launch_bounds__(256) void trans_k(const float* __restrict__ x, u16* __restrict__ xt)
{
    __shared__ float LT[64 * 65];
    const int tid = threadIdx.x;
    const int n0 = blockIdx.x * 64;
    const int c0 = blockIdx.y * 64;
    const int b  = blockIdx.z;
    const int w = tid >> 6, ln = tid & 63;
#pragma unroll
    for (int s = 0; s < 16; ++s) {
        int c = s * 4 + w;
        LT[c * 65 + ln] = x[((size_t)(b * 512 + c0 + c)) * N_PIX + n0 + ln];
    }
    __syncthreads();
#pragma unroll
    for (int s = 0; s < 16; ++s) {
        int n = s * 4 + w;
        xt[((size_t)(b * N_PIX + n0 + n)) * 512 + c0 + ln] = f2bf(LT[ln * 65 + n]);
    }
}

// ---------------------------------------------------------------------------
// bf16 MFMA GEMM for conv1x1: out_t[n][o] = act(s*Wx+b) (+res)
// Tile 128o x 128n, BK=32, 8 waves (4 o-strips x 2 n-halves), dbuf LDS,
// global_load_lds width-16. Activations transposed (b, n, c).
// out32: LDS-bounce transpose epilogue -> coalesced fp32 (b,o,n) writes.
// vsep: o-block=head; Q strip (wr==0) pre-scaled by QSC; V strips (wr>=2)
// diverted to plane layout.
// ---------------------------------------------------------------------------
__global__ __launch_bounds__(512) void gemm_k(
    const u16* __restrict__ Xt, int xcs, int xcoff,
    const u16* __restrict__ Wb, int Cin,
    const float* __restrict__ sc, const float* __restrict__ bi,
    const u16* __restrict__ res, int rcs, int rcoff,
    u16* __restrict__ out, int ocs, int ocoff,
    float* __restrict__ out32,
    u16* __restrict__ vsep,
    int act)
{
    __shared__ __align__(16) u16 WT[2][128 * 32];
    __shared__ __align__(16) u16 XT[2][128 * 32];
    const int tid  = threadIdx.x;
    const int lane = tid & 63;
    const int w    = __builtin_amdgcn_readfirstlane(tid >> 6);
    const int wr = w & 3;        // o-strip of 32
    const int wc = w >> 2;       // n-half of 64
    const int n0 = blockIdx.x * 128;
    const int o0 = blockIdx.y * 128;
    const int b  = blockIdx.z;
    const int l4 = lane >> 4, l15 = lane & 15;

    const int srow = tid >> 2;
    const int skc  = (tid & 3) * 8;
    const u16* wg = Wb + (size_t)(o0 + srow) * Cin + skc;
    const u16* xg = Xt + ((size_t)(b * N_PIX + n0 + srow)) * xcs + xcoff + skc;

    f32x4 acc[2][4];
#pragma unroll
    for (int i = 0; i < 2; ++i)
#pragma unroll
        for (int j = 0; j < 4; ++j) acc[i][j] = (f32x4){0.f, 0.f, 0.f, 0.f};

    const int nk = Cin >> 5;
    gl_lds16(wg, &WT[0][tid * 8]);
    gl_lds16(xg, &XT[0][tid * 8]);
    __syncthreads();

    for (int kk = 0; kk < nk; ++kk) {
        const int cur = kk & 1;
        if (kk + 1 < nk) {
            const int cc = (kk + 1) << 5;
            gl_lds16(wg + cc, &WT[cur ^ 1][tid * 8]);
            gl_lds16(xg + cc, &XT[cur ^ 1][tid * 8]);
        }
        short8 af[2], bfr[4];
#pragma unroll
        for (int i = 0; i < 2; ++i)
            af[i] = *(const short8*)&WT[cur][(wr * 32 + i * 16 + l15) * 32 + l4 * 8];
#pragma unroll
        for (int j = 0; j < 4; ++j)
            bfr[j] = *(const short8*)&XT[cur][(wc * 64 + j * 16 + l15) * 32 + l4 * 8];
#pragma unroll
        for (int i = 0; i < 2; ++i)
#pragma unroll
            for (int j = 0; j < 4; ++j)
                acc[i][j] = mfma16(af[i], bfr[j], acc[i][j]);
        __syncthreads();
    }

    if (out32) {
        const int Cout = gridDim.y * 128;
        float* eplds = (float*)XT;
        const int row = tid >> 4, cb = (tid & 15) * 8;
#pragma unroll
        for (int hh = 0; hh < 4; ++hh) {
            if (wr == hh) {
#pragma unroll
                for (int i = 0; i < 2; ++i)
#pragma unroll
                    for (int j = 0; j < 4; ++j)
#pragma unroll
                        for (int r = 0; r < 4; ++r) {
                            const int oo = i * 16 + l4 * 4 + r;
                            const int go = o0 + hh * 32 + oo;
                            float v = acc[i][j][r] * sc[go] + bi[go];
                            if (act) v = silu_f(v);
                            eplds[oo * 128 + wc * 64 + j * 16 + l15] = v;
                        }
            }
            __syncthreads();
            const size_t gidx = ((size_t)b * Cout + o0 + hh * 32 + row) * N_PIX + n0 + cb;
            f32x4 a0 = *(const f32x4*)&eplds[row * 128 + cb];
            f32x4 a1 = *(const f32x4*)&eplds[row * 128 + cb + 4];
            *(f32x4*)&out32[gidx]     = a0;
            *(f32x4*)&out32[gidx + 4] = a1;
            __syncthreads();
        }
        return;
    }

    const bool is_v = (vsep != nullptr) && (wr >= 2);
    const float qmul = (vsep != nullptr && wr == 0) ? QSC : 1.f;
#pragma unroll
    for (int i = 0; i < 2; ++i) {
        const int ob = o0 + wr * 32 + i * 16 + l4 * 4;
        float s4[4], b4[4];
#pragma unroll
        for (int r = 0; r < 4; ++r) { s4[r] = sc[ob + r] * qmul; b4[r] = bi[ob + r] * qmul; }
#pragma unroll
        for (int j = 0; j < 4; ++j) {
            const int n = n0 + wc * 64 + j * 16 + l15;
            float v[4];
#pragma unroll
            for (int r = 0; r < 4; ++r) {
                v[r] = acc[i][j][r] * s4[r] + b4[r];
                if (act) v[r] = silu_f(v[r]);
            }
            if (is_v) {
                const int hh = ob >> 7;
                const int dv = (ob & 127) - 64;
                u16* vp = vsep + (((size_t)(b * 4 + hh)) * 64 + dv) * N_PIX + n;
#pragma unroll
                for (int r = 0; r < 4; ++r) vp[r * N_PIX] = f2bf(v[r]);
            } else {
                const size_t base = ((size_t)(b * N_PIX + n)) * ocs + ocoff + ob;
                if (res) {
                    ushort4v rr = *(const ushort4v*)&res[((size_t)(b * N_PIX + n)) * rcs + rcoff + ob];
#pragma unroll
                    for (int r = 0; r < 4; ++r) v[r] += bf2f(rr[r]);
                }
                ushort4v pk;
#pragma unroll
                for (int r = 0; r < 4; ++r) pk[r] = f2bf(v[r]);
                *(ushort4v*)&out[base] = pk;
            }
        }
    }
}

// ---------------------------------------------------------------------------
// Fused flash attention, zero-staging version.
// grid (16, 4, 16), 256 threads = 4 waves x 16 q-rows. KV tile = 64.
// K/V fragments loaded DIRECTLY from global (L1/L2-resident; no LDS staging,
// no barriers). Softmax in exp2 domain (Q pre-scaled by QSC in qkv GEMM),
// DPP 16-lane max reduce, defer-max (T13). LDS = wave-private P only (9.2KB).
// ---------------------------------------------------------------------------
__global__ __launch_bounds__(256, 4) void attn_k(
    const u16* __restrict__ qkvt, const u16* __restrict__ vsep,
    u16* __restrict__ xat)
{
    __shared__ __align__(16) u16 PL[4 * 16 * 72];
    const int tid  = threadIdx.x;
    const int lane = tid & 63;
    const int w    = __builtin_amdgcn_readfirstlane(tid >> 6);
    const int l4 = lane >> 4, l15 = lane & 15;
    const int h = blockIdx.y, b = blockIdx.z;
    const int n0w = blockIdx.x * 64 + w * 16;
    u16* PLw = PL + w * 16 * 72;

    const short8 qf = *(const short8*)&qkvt[((size_t)(b * N_PIX + n0w + l15)) * 512 + h * 128 + l4 * 8];
    // fragment-natural global bases: l15 -> row, l4 -> 16B k-chunk
    const u16* kb = qkvt + ((size_t)(b * N_PIX + l15)) * 512 + h * 128 + 32 + l4 * 8;
    const u16* vb = vsep + (((size_t)(b * 4 + h)) * 64 + l15) * N_PIX + l4 * 8;

    float mrun[4], lrun[4];
#pragma unroll
    for (int r = 0; r < 4; ++r) { mrun[r] = -1e30f; lrun[r] = 0.f; }
    f32x4 accv[4];
#pragma unroll
    for (int d = 0; d < 4; ++d) accv[d] = (f32x4){0.f, 0.f, 0.f, 0.f};
    const f32x4 z4 = {0.f, 0.f, 0.f, 0.f};

    for (int t = 0; t < 16; ++t) {
        const int m0 = t * 64;
        // K fragments (4 x b128, 64-key x 32-d tile)
        short8 kf[4];
#pragma unroll
        for (int mt = 0; mt < 4; ++mt)
            kf[mt] = *(const short8*)(kb + (size_t)(m0 + mt * 16) * 512);
        // V fragments (8 x b128) issued early so latency hides under softmax
        short8 vf[2][4];
#pragma unroll
        for (int mq = 0; mq < 2; ++mq)
#pragma unroll
            for (int d = 0; d < 4; ++d)
                vf[mq][d] = *(const short8*)(vb + (size_t)(d * 16) * N_PIX + m0 + mq * 32);

        f32x4 s[4];
        __builtin_amdgcn_s_setprio(1);
#pragma unroll
        for (int mt = 0; mt < 4; ++mt) s[mt] = mfma16(qf, kf[mt], z4);
        __builtin_amdgcn_s_setprio(0);

        // tile max per q-row (exp2 domain; Q pre-scaled)
        float tm[4], g = -1e30f;
#pragma unroll
        for (int r = 0; r < 4; ++r) {
            float m_ = fmaxf(fmaxf(s[0][r], s[1][r]), fmaxf(s[2][r], s[3][r]));
            tm[r] = dpp_max16(m_);
            g = fmaxf(g, tm[r] - mrun[r]);
        }
        // defer-max: rescale only when some row grew past threshold (wave-uniform)
        if (!__all(g <= 11.0f)) {
#pragma unroll
            for (int r = 0; r < 4; ++r) {
                float mnew = fmaxf(mrun[r], tm[r]);
                float corr = exp2_f(mrun[r] - mnew);
                mrun[r] = mnew;
                lrun[r] *= corr;
#pragma unroll
                for (int d = 0; d < 4; ++d) accv[d][r] *= corr;
            }
        }
#pragma unroll
        for (int mt = 0; mt < 4; ++mt)
#pragma unroll
            for (int r = 0; r < 4; ++r) {
                float p = exp2_f(s[mt][r] - mrun[r]);
                lrun[r] += p;
                PLw[(l4 * 4 + r) * 72 + mt * 16 + l15] = f2bf(p);
            }

        __builtin_amdgcn_s_setprio(1);
#pragma unroll
        for (int mq = 0; mq < 2; ++mq) {
            short8 pa = *(const short8*)&PLw[l15 * 72 + mq * 32 + l4 * 8];
#pragma unroll
            for (int d = 0; d < 4; ++d)
                accv[d] = mfma16(pa, vf[mq][d], accv[d]);
        }
        __builtin_amdgcn_s_setprio(0);
    }

#pragma unroll
    for (int r = 0; r < 4; ++r)
        lrun[r] = 1.f / dpp_sum16(lrun[r]);
#pragma unroll
    for (int d = 0; d < 4; ++d)
#pragma unroll
        for (int r = 0; r < 4; ++r) {
            const int n = n0w + l4 * 4 + r;
            xat[((size_t)(b * N_PIX + n)) * 256 + h * 64 + d * 16 + l15] =
                f2bf(accv[d][r] * lrun[r]);
        }
}

// ---------------------------------------------------------------------------
// Depthwise 3x3 on V planes (v_sep), scale+bias, accumulate into xa_t.
// ---------------------------------------------------------------------------
__global__ __launch_bounds__(256) void pe_k(
    const u16* __restrict__ vsep, const float* __restrict__ Wpe,
    const float* __restrict__ spe, const float* __restrict__ bpe,
    u16* __restrict__ xat)
{
    const int t  = threadIdx.x;          // channel
    const int y0 = blockIdx.x * 2;
    const int b  = blockIdx.y;
    const u16* vp = vsep + ((size_t)(b * 256 + t)) * N_PIX;

    float rv[128];
#pragma unroll
    for (int rr = 0; rr < 4; ++rr) {
        const int yy = y0 - 1 + rr;
        if (yy >= 0 && yy < 32) {
#pragma unroll
            for (int g = 0; g < 4; ++g) {
                uint4v u = *(const uint4v*)&vp[yy * 32 + g * 8];
#pragma unroll
                for (int e = 0; e < 4; ++e) {
                    rv[rr * 32 + g * 8 + e * 2]     = bf2f((u16)(u[e] & 0xffff));
                    rv[rr * 32 + g * 8 + e * 2 + 1] = bf2f((u16)(u[e] >> 16));
                }
            }
        } else {
#pragma unroll
            for (int j = 0; j < 32; ++j) rv[rr * 32 + j] = 0.f;
        }
    }
    float w9[9];
#pragma unroll
    for (int i = 0; i < 9; ++i) w9[i] = Wpe[t * 9 + i];
    const float scv = spe[t], biv = bpe[t];
    u16* xp = xat + ((size_t)(b * N_PIX)) * 256 + t;

#pragma unroll
    for (int py = 0; py < 2; ++py)
#pragma unroll
        for (int px = 0; px < 32; ++px) {
            float a = 0.f;
#pragma unroll
            for (int ky = 0; ky < 3; ++ky) {
                const int lr = py + ky;
#pragma unroll
                for (int kx = 0; kx < 3; ++kx) {
                    const int xx = px + kx - 1;
                    if (xx >= 0 && xx < 32)
                        a = fmaf(w9[ky * 3 + kx], rv[lr * 32 + xx], a);
                }
            }
            const int n = (y0 + py) * 32 + px;
            u16* p = xp + (size_t)n * 256;
            *p = f2bf(bf2f(*p) + a * scv + biv);
        }
}

extern "C" void kernel_launch(void* const* d_in, const int* in_sizes, int n_in,
                              void* d_out, int out_size, void* d_ws, size_t ws_size,
                              hipStream_t stream)
{
    const float* x      = (const float*)d_in[0];
    const float* W_cv1  = (const float*)d_in[1];
    const float* s_cv1  = (const float*)d_in[2];
    const float* b_cv1  = (const float*)d_in[3];
    const float* W_qkv  = (const float*)d_in[4];
    const float* s_qkv  = (const float*)d_in[5];
    const float* b_qkv  = (const float*)d_in[6];
    const float* W_proj = (const float*)d_in[7];
    const float* s_proj = (const float*)d_in[8];
    const float* b_proj = (const float*)d_in[9];
    const float* W_pe   = (const float*)d_in[10];
    const float* s_pe   = (const float*)d_in[11];
    const float* b_pe   = (const float*)d_in[12];
    const float* W_ffn1 = (const float*)d_in[13];
    const float* s_ffn1 = (const float*)d_in[14];
    const float* b_ffn1 = (const float*)d_in[15];
    const float* W_ffn2 = (const float*)d_in[16];
    const float* s_ffn2 = (const float*)d_in[17];
    const float* b_ffn2 = (const float*)d_in[18];
    const float* W_cv2  = (const float*)d_in[19];
    const float* s_cv2  = (const float*)d_in[20];
    const float* b_cv2  = (const float*)d_in[21];

    u16* ws = (u16*)d_ws;
    u16* xt      = ws;                    // 16*1024*512
    u16* yt      = xt + 8388608;
    u16* qkvt    = yt + 8388608;
    u16* fft     = qkvt + 8388608;
    u16* vsep    = fft + 8388608;         // 16*256*1024
    u16* xat     = vsep + 4194304;        // 16*1024*256
    u16* wb_cv1  = xat + 4194304;
    u16* wb_qkv  = wb_cv1 + 262144;
    u16* wb_proj = wb_qkv + 131072;
    u16* wb_ffn1 = wb_proj + 65536;
    u16* wb_ffn2 = wb_ffn1 + 131072;
    u16* wb_cv2  = wb_ffn2 + 131072;

    cvtw_k<<<dim3(64, 6), 256, 0, stream>>>(
        W_cv1, wb_cv1, 512 * 512, W_qkv, wb_qkv, 512 * 256,
        W_proj, wb_proj, 256 * 256, W_ffn1, wb_ffn1, 512 * 256,
        W_ffn2, wb_ffn2, 256 * 512, W_cv2, wb_cv2, 512 * 512);
    trans_k<<<dim3(16, 8, 16), 256, 0, stream>>>(x, xt);

    // cv1: y_t = silu(W_cv1 x)   (512 out)
    gemm_k<<<dim3(8, 4, 16), 512, 0, stream>>>(
        xt, 512, 0, wb_cv1, 512, s_cv1, b_cv1,
        nullptr, 0, 0, yt, 512, 0, nullptr, nullptr, 1);
    // qkv from bb = y_t[:,:,256:]; Q pre-scaled by QSC; V to plane layout
    gemm_k<<<dim3(8, 4, 16), 512, 0, stream>>>(
        yt, 512, 256, wb_qkv, 256, s_qkv, b_qkv,
        nullptr, 0, 0, qkvt, 512, 0, nullptr, vsep, 0);
    // fused flash attention -> xa_t
    attn_k<<<dim3(16, 4, 16), 256, 0, stream>>>(qkvt, vsep, xat);
    // xa_t += dwconv3(v)
    pe_k<<<dim3(16, 16), 256, 0, stream>>>(vsep, W_pe, s_pe, b_pe, xat);
    // proj + residual, in-place into y_t[:,:,256:]
    gemm_k<<<dim3(8, 2, 16), 512, 0, stream>>>(
        xat, 256, 0, wb_proj, 256, s_proj, b_proj,
        yt, 512, 256, yt, 512, 256, nullptr, nullptr, 0);
    // ffn1
    gemm_k<<<dim3(8, 4, 16), 512, 0, stream>>>(
        yt, 512, 256, wb_ffn1, 256, s_ffn1, b_ffn1,
        nullptr, 0, 0, fft, 512, 0, nullptr, nullptr, 1);
    // ffn2 + residual, in-place into y_t[:,:,256:]
    gemm_k<<<dim3(8, 2, 16), 512, 0, stream>>>(
        fft, 512, 0, wb_ffn2, 512, s_ffn2, b_ffn2,
        yt, 512, 256, yt, 512, 256, nullptr, nullptr, 0);
    // cv2 on concat(a, bb) = y_t[:,:,0:512] -> d_out fp32 (b, 512, 1024)
    gemm_k<<<dim3(8, 4, 16), 512, 0, stream>>>(
        yt, 512, 0, wb_cv2, 512, s_cv2, b_cv2,
        nullptr, 0, 0, nullptr, 0, 0, (float*)d_out, nullptr, 1);
}

// Round 11
// 268.394 us; speedup vs baseline: 1.1934x; 1.1934x over previous
//
#include <hip/hip_runtime.h>

typedef unsigned short u16;
typedef __attribute__((ext_vector_type(8))) short short8;
typedef __attribute__((ext_vector_type(4))) float f32x4;
typedef __attribute__((ext_vector_type(4))) unsigned int uint4v;
typedef __attribute__((ext_vector_type(4))) unsigned short ushort4v;

#define N_PIX 1024
constexpr float QSC = 0.25506626725324577f;   // 32^-0.5 * log2(e)

__device__ __forceinline__ float bf2f(u16 v) {
    unsigned u = ((unsigned)v) << 16;
    return __builtin_bit_cast(float, u);
}
__device__ __forceinline__ u16 f2bf(float f) {
    unsigned u = __builtin_bit_cast(unsigned, f);
    u += 0x7fff + ((u >> 16) & 1);
    return (u16)(u >> 16);
}
__device__ __forceinline__ u16 f2bf_fast(float f) {   // round-half-up, 2 VALU
    unsigned u = __builtin_bit_cast(unsigned, f);
    return (u16)((u + 0x8000u) >> 16);
}
__device__ __forceinline__ float silu_f(float x) { return x / (1.f + __expf(-x)); }

__device__ __forceinline__ float exp2_f(float x) {
    float r; asm("v_exp_f32 %0, %1" : "=v"(r) : "v"(x)); return r;
}

__device__ __forceinline__ f32x4 mfma16(short8 a, short8 b, f32x4 c) {
    return __builtin_amdgcn_mfma_f32_16x16x32_bf16(a, b, c, 0, 0, 0);
}

__device__ __forceinline__ void gl_lds16(const u16* g, u16* l) {
    __builtin_amdgcn_global_load_lds(
        (const __attribute__((address_space(1))) unsigned int*)g,
        (__attribute__((address_space(3))) unsigned int*)l, 16, 0, 0);
}

// 16-lane (DPP-row) reduces (verified round 9)
__device__ __forceinline__ float dpp_max16(float x) {
    int v = __builtin_bit_cast(int, x);
    x = fmaxf(x, __builtin_bit_cast(float, __builtin_amdgcn_mov_dpp(v, 0xB1, 0xF, 0xF, true)));
    v = __builtin_bit_cast(int, x);
    x = fmaxf(x, __builtin_bit_cast(float, __builtin_amdgcn_mov_dpp(v, 0x4E, 0xF, 0xF, true)));
    v = __builtin_bit_cast(int, x);
    x = fmaxf(x, __builtin_bit_cast(float, __builtin_amdgcn_mov_dpp(v, 0x141, 0xF, 0xF, true)));
    v = __builtin_bit_cast(int, x);
    x = fmaxf(x, __builtin_bit_cast(float, __builtin_amdgcn_mov_dpp(v, 0x140, 0xF, 0xF, true)));
    return x;
}
__device__ __forceinline__ float dpp_sum16(float x) {
    int v = __builtin_bit_cast(int, x);
    x += __builtin_bit_cast(float, __builtin_amdgcn_mov_dpp(v, 0xB1, 0xF, 0xF, true));
    v = __builtin_bit_cast(int, x);
    x += __builtin_bit_cast(float, __builtin_amdgcn_mov_dpp(v, 0x4E, 0xF, 0xF, true));
    v = __builtin_bit_cast(int, x);
    x += __builtin_bit_cast(float, __builtin_amdgcn_mov_dpp(v, 0x141, 0xF, 0xF, true));
    v = __builtin_bit_cast(int, x);
    x += __builtin_bit_cast(float, __builtin_amdgcn_mov_dpp(v, 0x140, 0xF, 0xF, true));
    return x;
}

// ---------------------------------------------------------------------------
// Weight fp32 -> bf16 conversion (6 segments, blockIdx.y selects)
// ---------------------------------------------------------------------------
__global__ void cvtw_k(const float* s0, u16* d0, int n0,
                       const float* s1, u16* d1, int n1,
                       const float* s2, u16* d2, int n2,
                       const float* s3, u16* d3, int n3,
                       const float* s4, u16* d4, int n4,
                       const float* s5, u16* d5, int n5)
{
    const float* sp = nullptr; u16* dp = nullptr; int n = 0;
    switch (blockIdx.y) {
        case 0: sp = s0; dp = d0; n = n0; break;
        case 1: sp = s1; dp = d1; n = n1; break;
        case 2: sp = s2; dp = d2; n = n2; break;
        case 3: sp = s3; dp = d3; n = n3; break;
        case 4: sp = s4; dp = d4; n = n4; break;
        case 5: sp = s5; dp = d5; n = n5; break;
    }
    for (int i = blockIdx.x * 256 + threadIdx.x; i < n; i += gridDim.x * 256)
        dp[i] = f2bf(sp[i]);
}

// ---------------------------------------------------------------------------
// x (b, 512, 1024) fp32 -> x_t (b, 1024, 512) bf16  (LDS-tiled transpose)
// ---------------------------------------------------------------------------
__global__ __launch_bounds__(256) void trans_k(const float* __restrict__ x, u16* __restrict__ xt)
{
    __shared__ float LT[64 * 65];
    const int tid = threadIdx.x;
    const int n0 = blockIdx.x * 64;
    const int c0 = blockIdx.y * 64;
    const int b  = blockIdx.z;
    const int w = tid >> 6, ln = tid & 63;
#pragma unroll
    for (int s = 0; s < 16; ++s) {
        int c = s * 4 + w;
        LT[c * 65 + ln] = x[((size_t)(b * 512 + c0 + c)) * N_PIX + n0 + ln];
    }
    __syncthreads();
#pragma unroll
    for (int s = 0; s < 16; ++s) {
        int n = s * 4 + w;
        xt[((size_t)(b * N_PIX + n0 + n)) * 512 + c0 + ln] = f2bf(LT[ln * 65 + n]);
    }
}

// ---------------------------------------------------------------------------
// bf16 MFMA GEMM for conv1x1: out_t[n][o] = act(s*Wx+b) (+res)
// Tile 128o x 128n, BK=32, 8 waves (4 o-strips x 2 n-halves).
// 3-stage LDS pipeline with COUNTED vmcnt (T4): issue tile t+2 after the
// barrier, wait vmcnt(4) (t+1/t+2 stay in flight) — never drain to 0 mid-loop.
// out32: LDS-bounce transpose epilogue. vsep: Q strip pre-scaled by QSC,
// V strips diverted to plane layout.
// ---------------------------------------------------------------------------
__global__ __launch_bounds__(512) void gemm_k(
    const u16* __restrict__ Xt, int xcs, int xcoff,
    const u16* __restrict__ Wb, int Cin,
    const float* __restrict__ sc, const float* __restrict__ bi,
    const u16* __restrict__ res, int rcs, int rcoff,
    u16* __restrict__ out, int ocs, int ocoff,
    float* __restrict__ out32,
    u16* __restrict__ vsep,
    int act)
{
    __shared__ __align__(16) u16 WT[3][128 * 32];
    __shared__ __align__(16) u16 XT[3][128 * 32];
    const int tid  = threadIdx.x;
    const int lane = tid & 63;
    const int w    = __builtin_amdgcn_readfirstlane(tid >> 6);
    const int wr = w & 3;        // o-strip of 32
    const int wc = w >> 2;       // n-half of 64
    const int n0 = blockIdx.x * 128;
    const int o0 = blockIdx.y * 128;
    const int b  = blockIdx.z;
    const int l4 = lane >> 4, l15 = lane & 15;

    const int srow = tid >> 2;
    const int skc  = (tid & 3) * 8;
    const u16* wg = Wb + (size_t)(o0 + srow) * Cin + skc;
    const u16* xg = Xt + ((size_t)(b * N_PIX + n0 + srow)) * xcs + xcoff + skc;

    f32x4 acc[2][4];
#pragma unroll
    for (int i = 0; i < 2; ++i)
#pragma unroll
        for (int j = 0; j < 4; ++j) acc[i][j] = (f32x4){0.f, 0.f, 0.f, 0.f};

    const int nk = Cin >> 5;
    // prologue: tiles 0 and 1 in flight; wait tile 0 only
    gl_lds16(wg,      &WT[0][tid * 8]);
    gl_lds16(xg,      &XT[0][tid * 8]);
    gl_lds16(wg + 32, &WT[1][tid * 8]);
    gl_lds16(xg + 32, &XT[1][tid * 8]);
    asm volatile("s_waitcnt vmcnt(2)" ::: "memory");
    __builtin_amdgcn_s_barrier();
    __builtin_amdgcn_sched_barrier(0);

    for (int kk = 0; kk < nk; ++kk) {
        const int cur = kk % 3;
        if (kk + 2 < nk) {
            const int cc = (kk + 2) << 5;
            const int nb = (kk + 2) % 3;
            gl_lds16(wg + cc, &WT[nb][tid * 8]);
            gl_lds16(xg + cc, &XT[nb][tid * 8]);
            asm volatile("s_waitcnt vmcnt(4)" ::: "memory");   // tile kk ready
        } else if (kk + 1 < nk) {
            asm volatile("s_waitcnt vmcnt(2)" ::: "memory");
        } else {
            asm volatile("s_waitcnt vmcnt(0)" ::: "memory");
        }
        short8 af[2], bfr[4];
#pragma unroll
        for (int i = 0; i < 2; ++i)
            af[i] = *(const short8*)&WT[cur][(wr * 32 + i * 16 + l15) * 32 + l4 * 8];
#pragma unroll
        for (int j = 0; j < 4; ++j)
            bfr[j] = *(const short8*)&XT[cur][(wc * 64 + j * 16 + l15) * 32 + l4 * 8];
        __builtin_amdgcn_s_setprio(1);
#pragma unroll
        for (int i = 0; i < 2; ++i)
#pragma unroll
            for (int j = 0; j < 4; ++j)
                acc[i][j] = mfma16(af[i], bfr[j], acc[i][j]);
        __builtin_amdgcn_s_setprio(0);
        __builtin_amdgcn_s_barrier();       // readers of buf (kk+2)%3 done
        __builtin_amdgcn_sched_barrier(0);
    }

    if (out32) {
        const int Cout = gridDim.y * 128;
        float* eplds = (float*)XT;
        const int row = tid >> 4, cb = (tid & 15) * 8;
#pragma unroll
        for (int hh = 0; hh < 4; ++hh) {
            if (wr == hh) {
#pragma unroll
                for (int i = 0; i < 2; ++i)
#pragma unroll
                    for (int j = 0; j < 4; ++j)
#pragma unroll
                        for (int r = 0; r < 4; ++r) {
                            const int oo = i * 16 + l4 * 4 + r;
                            const int go = o0 + hh * 32 + oo;
                            float v = acc[i][j][r] * sc[go] + bi[go];
                            if (act) v = silu_f(v);
                            eplds[oo * 128 + wc * 64 + j * 16 + l15] = v;
                        }
            }
            __syncthreads();
            const size_t gidx = ((size_t)b * Cout + o0 + hh * 32 + row) * N_PIX + n0 + cb;
            f32x4 a0 = *(const f32x4*)&eplds[row * 128 + cb];
            f32x4 a1 = *(const f32x4*)&eplds[row * 128 + cb + 4];
            *(f32x4*)&out32[gidx]     = a0;
            *(f32x4*)&out32[gidx + 4] = a1;
            __syncthreads();
        }
        return;
    }

    const bool is_v = (vsep != nullptr) && (wr >= 2);
    const float qmul = (vsep != nullptr && wr == 0) ? QSC : 1.f;
#pragma unroll
    for (int i = 0; i < 2; ++i) {
        const int ob = o0 + wr * 32 + i * 16 + l4 * 4;
        float s4[4], b4[4];
#pragma unroll
        for (int r = 0; r < 4; ++r) { s4[r] = sc[ob + r] * qmul; b4[r] = bi[ob + r] * qmul; }
#pragma unroll
        for (int j = 0; j < 4; ++j) {
            const int n = n0 + wc * 64 + j * 16 + l15;
            float v[4];
#pragma unroll
            for (int r = 0; r < 4; ++r) {
                v[r] = acc[i][j][r] * s4[r] + b4[r];
                if (act) v[r] = silu_f(v[r]);
            }
            if (is_v) {
                const int hh = ob >> 7;
                const int dv = (ob & 127) - 64;
                u16* vp = vsep + (((size_t)(b * 4 + hh)) * 64 + dv) * N_PIX + n;
#pragma unroll
                for (int r = 0; r < 4; ++r) vp[r * N_PIX] = f2bf(v[r]);
            } else {
                const size_t base = ((size_t)(b * N_PIX + n)) * ocs + ocoff + ob;
                if (res) {
                    ushort4v rr = *(const ushort4v*)&res[((size_t)(b * N_PIX + n)) * rcs + rcoff + ob];
#pragma unroll
                    for (int r = 0; r < 4; ++r) v[r] += bf2f(rr[r]);
                }
                ushort4v pk;
#pragma unroll
                for (int r = 0; r < 4; ++r) pk[r] = f2bf(v[r]);
                *(ushort4v*)&out[base] = pk;
            }
        }
    }
}

// ---------------------------------------------------------------------------
// Fused flash attention — round-8 staged structure (verified 52.5us) with
// verified numeric tweaks from round 9: exp2-domain softmax (Q pre-scaled),
// DPP reduces, defer-max, cheap P pack. KV tile 64, dbuf K/V LDS, T14
// async-STAGE split, one barrier/tile, T5 setprio.
// ---------------------------------------------------------------------------
__global__ __launch_bounds__(256) void attn_k(
    const u16* __restrict__ qkvt, const u16* __restrict__ vsep,
    u16* __restrict__ xat)
{
    __shared__ __align__(16) u16 KT[2][64 * 40];   // [m][d] pad 40
    __shared__ __align__(16) u16 VT[2][64 * 72];   // [dv][m] pad 72
    __shared__ __align__(16) u16 PL[4 * 16 * 72];  // per-wave P rows
    const int tid  = threadIdx.x;
    const int lane = tid & 63;
    const int w    = __builtin_amdgcn_readfirstlane(tid >> 6);
    const int l4 = lane >> 4, l15 = lane & 15;
    const int h = blockIdx.y, b = blockIdx.z;
    const int n0w = blockIdx.x * 64 + w * 16;
    u16* PLw = PL + w * 16 * 72;

    const short8 qf = *(const short8*)&qkvt[((size_t)(b * N_PIX + n0w + l15)) * 512 + h * 128 + l4 * 8];

    const int skr = tid >> 2, skc = (tid & 3) * 8;          // K: row, d-col
    const int svd = tid >> 3, svm = (tid & 7) * 8;          // V: dv, m-col
    const u16* kgbase = qkvt + ((size_t)(b * N_PIX + skr)) * 512 + h * 128 + 32 + skc;
    const u16* vgbase = vsep + (((size_t)(b * 4 + h)) * 64 + svd) * N_PIX + svm;

    float mrun[4], lrun[4];
#pragma unroll
    for (int r = 0; r < 4; ++r) { mrun[r] = -1e30f; lrun[r] = 0.f; }
    f32x4 accv[4];
#pragma unroll
    for (int d = 0; d < 4; ++d) accv[d] = (f32x4){0.f, 0.f, 0.f, 0.f};
    const f32x4 z4 = {0.f, 0.f, 0.f, 0.f};

    uint4v kreg = *(const uint4v*)(kgbase);
    uint4v vr0  = *(const uint4v*)(vgbase);
    uint4v vr1  = *(const uint4v*)(vgbase + 32 * N_PIX);

    for (int t = 0; t < 16; ++t) {
        const int cur = t & 1;
        *(uint4v*)&KT[cur][skr * 40 + skc] = kreg;
        *(uint4v*)&VT[cur][svd * 72 + svm] = vr0;
        *(uint4v*)&VT[cur][(svd + 32) * 72 + svm] = vr1;
        if (t < 15) {
            const int m1 = (t + 1) * 64;
            kreg = *(const uint4v*)(kgbase + (size_t)m1 * 512);
            vr0  = *(const uint4v*)(vgbase + m1);
            vr1  = *(const uint4v*)(vgbase + 32 * N_PIX + m1);
        }
        __syncthreads();

        f32x4 s[4];
        __builtin_amdgcn_s_setprio(1);
#pragma unroll
        for (int mt = 0; mt < 4; ++mt) {
            short8 kf = *(const short8*)&KT[cur][(mt * 16 + l15) * 40 + l4 * 8];
            s[mt] = mfma16(qf, kf, z4);
        }
        __builtin_amdgcn_s_setprio(0);

        // tile max (exp2 domain; Q pre-scaled by QSC)
        float tm[4], g = -1e30f;
#pragma unroll
        for (int r = 0; r < 4; ++r) {
            float m_ = fmaxf(fmaxf(s[0][r], s[1][r]), fmaxf(s[2][r], s[3][r]));
            tm[r] = dpp_max16(m_);
            g = fmaxf(g, tm[r] - mrun[r]);
        }
        if (!__all(g <= 11.0f)) {          // defer-max (T13)
#pragma unroll
            for (int r = 0; r < 4; ++r) {
                float mnew = fmaxf(mrun[r], tm[r]);
                float corr = exp2_f(mrun[r] - mnew);
                mrun[r] = mnew;
                lrun[r] *= corr;
#pragma unroll
                for (int d = 0; d < 4; ++d) accv[d][r] *= corr;
            }
        }
#pragma unroll
        for (int mt = 0; mt < 4; ++mt)
#pragma unroll
            for (int r = 0; r < 4; ++r) {
                float p = exp2_f(s[mt][r] - mrun[r]);
                lrun[r] += p;
                PLw[(l4 * 4 + r) * 72 + mt * 16 + l15] = f2bf_fast(p);
            }

        __builtin_amdgcn_s_setprio(1);
#pragma unroll
        for (int mq = 0; mq < 2; ++mq) {
            short8 pa = *(const short8*)&PLw[l15 * 72 + mq * 32 + l4 * 8];
#pragma unroll
            for (int d = 0; d < 4; ++d) {
                short8 vf = *(const short8*)&VT[cur][(d * 16 + l15) * 72 + mq * 32 + l4 * 8];
                accv[d] = mfma16(pa, vf, accv[d]);
            }
        }
        __builtin_amdgcn_s_setprio(0);
    }

#pragma unroll
    for (int r = 0; r < 4; ++r)
        lrun[r] = 1.f / dpp_sum16(lrun[r]);
#pragma unroll
    for (int d = 0; d < 4; ++d)
#pragma unroll
        for (int r = 0; r < 4; ++r) {
            const int n = n0w + l4 * 4 + r;
            xat[((size_t)(b * N_PIX + n)) * 256 + h * 64 + d * 16 + l15] =
                f2bf(accv[d][r] * lrun[r]);
        }
}

// ---------------------------------------------------------------------------
// Depthwise 3x3 on V planes (v_sep), scale+bias, accumulate into xa_t.
// ---------------------------------------------------------------------------
__global__ __launch_bounds__(256) void pe_k(
    const u16* __restrict__ vsep, const float* __restrict__ Wpe,
    const float* __restrict__ spe, const float* __restrict__ bpe,
    u16* __restrict__ xat)
{
    const int t  = threadIdx.x;          // channel
    const int y0 = blockIdx.x * 2;
    const int b  = blockIdx.y;
    const u16* vp = vsep + ((size_t)(b * 256 + t)) * N_PIX;

    float rv[128];
#pragma unroll
    for (int rr = 0; rr < 4; ++rr) {
        const int yy = y0 - 1 + rr;
        if (yy >= 0 && yy < 32) {
#pragma unroll
            for (int g = 0; g < 4; ++g) {
                uint4v u = *(const uint4v*)&vp[yy * 32 + g * 8];
#pragma unroll
                for (int e = 0; e < 4; ++e) {
                    rv[rr * 32 + g * 8 + e * 2]     = bf2f((u16)(u[e] & 0xffff));
                    rv[rr * 32 + g * 8 + e * 2 + 1] = bf2f((u16)(u[e] >> 16));
                }
            }
        } else {
#pragma unroll
            for (int j = 0; j < 32; ++j) rv[rr * 32 + j] = 0.f;
        }
    }
    float w9[9];
#pragma unroll
    for (int i = 0; i < 9; ++i) w9[i] = Wpe[t * 9 + i];
    const float scv = spe[t], biv = bpe[t];
    u16* xp = xat + ((size_t)(b * N_PIX)) * 256 + t;

#pragma unroll
    for (int py = 0; py < 2; ++py)
#pragma unroll
        for (int px = 0; px < 32; ++px) {
            float a = 0.f;
#pragma unroll
            for (int ky = 0; ky < 3; ++ky) {
                const int lr = py + ky;
#pragma unroll
                for (int kx = 0; kx < 3; ++kx) {
                    const int xx = px + kx - 1;
                    if (xx >= 0 && xx < 32)
                        a = fmaf(w9[ky * 3 + kx], rv[lr * 32 + xx], a);
                }
            }
            const int n = (y0 + py) * 32 + px;
            u16* p = xp + (size_t)n * 256;
            *p = f2bf(bf2f(*p) + a * scv + biv);
        }
}

extern "C" void kernel_launch(void* const* d_in, const int* in_sizes, int n_in,
                              void* d_out, int out_size, void* d_ws, size_t ws_size,
                              hipStream_t stream)
{
    const float* x      = (const float*)d_in[0];
    const float* W_cv1  = (const float*)d_in[1];
    const float* s_cv1  = (const float*)d_in[2];
    const float* b_cv1  = (const float*)d_in[3];
    const float* W_qkv  = (const float*)d_in[4];
    const float* s_qkv  = (const float*)d_in[5];
    const float* b_qkv  = (const float*)d_in[6];
    const float* W_proj = (const float*)d_in[7];
    const float* s_proj = (const float*)d_in[8];
    const float* b_proj = (const float*)d_in[9];
    const float* W_pe   = (const float*)d_in[10];
    const float* s_pe   = (const float*)d_in[11];
    const float* b_pe   = (const float*)d_in[12];
    const float* W_ffn1 = (const float*)d_in[13];
    const float* s_ffn1 = (const float*)d_in[14];
    const float* b_ffn1 = (const float*)d_in[15];
    const float* W_ffn2 = (const float*)d_in[16];
    const float* s_ffn2 = (const float*)d_in[17];
    const float* b_ffn2 = (const float*)d_in[18];
    const float* W_cv2  = (const float*)d_in[19];
    const float* s_cv2  = (const float*)d_in[20];
    const float* b_cv2  = (const float*)d_in[21];

    u16* ws = (u16*)d_ws;
    u16* xt      = ws;                    // 16*1024*512
    u16* yt      = xt + 8388608;
    u16* qkvt    = yt + 8388608;
    u16* fft     = qkvt + 8388608;
    u16* vsep    = fft + 8388608;         // 16*256*1024
    u16* xat     = vsep + 4194304;        // 16*1024*256
    u16* wb_cv1  = xat + 4194304;
    u16* wb_qkv  = wb_cv1 + 262144;
    u16* wb_proj = wb_qkv + 131072;
    u16* wb_ffn1 = wb_proj + 65536;
    u16* wb_ffn2 = wb_ffn1 + 131072;
    u16* wb_cv2  = wb_ffn2 + 131072;

    cvtw_k<<<dim3(64, 6), 256, 0, stream>>>(
        W_cv1, wb_cv1, 512 * 512, W_qkv, wb_qkv, 512 * 256,
        W_proj, wb_proj, 256 * 256, W_ffn1, wb_ffn1, 512 * 256,
        W_ffn2, wb_ffn2, 256 * 512, W_cv2, wb_cv2, 512 * 512);
    trans_k<<<dim3(16, 8, 16), 256, 0, stream>>>(x, xt);

    // cv1: y_t = silu(W_cv1 x)   (512 out)
    gemm_k<<<dim3(8, 4, 16), 512, 0, stream>>>(
        xt, 512, 0, wb_cv1, 512, s_cv1, b_cv1,
        nullptr, 0, 0, yt, 512, 0, nullptr, nullptr, 1);
    // qkv from bb = y_t[:,:,256:]; Q pre-scaled by QSC; V to plane layout
    gemm_k<<<dim3(8, 4, 16), 512, 0, stream>>>(
        yt, 512, 256, wb_qkv, 256, s_qkv, b_qkv,
        nullptr, 0, 0, qkvt, 512, 0, nullptr, vsep, 0);
    // fused flash attention -> xa_t
    attn_k<<<dim3(16, 4, 16), 256, 0, stream>>>(qkvt, vsep, xat);
    // xa_t += dwconv3(v)
    pe_k<<<dim3(16, 16), 256, 0, stream>>>(vsep, W_pe, s_pe, b_pe, xat);
    // proj + residual, in-place into y_t[:,:,256:]
    gemm_k<<<dim3(8, 2, 16), 512, 0, stream>>>(
        xat, 256, 0, wb_proj, 256, s_proj, b_proj,
        yt, 512, 256, yt, 512, 256, nullptr, nullptr, 0);
    // ffn1
    gemm_k<<<dim3(8, 4, 16), 512, 0, stream>>>(
        yt, 512, 256, wb_ffn1, 256, s_ffn1, b_ffn1,
        nullptr, 0, 0, fft, 512, 0, nullptr, nullptr, 1);
    // ffn2 + residual, in-place into y_t[:,:,256:]
    gemm_k<<<dim3(8, 2, 16), 512, 0, stream>>>(
        fft, 512, 0, wb_ffn2, 512, s_ffn2, b_ffn2,
        yt, 512, 256, yt, 512, 256, nullptr, nullptr, 0);
    // cv2 on concat(a, bb) = y_t[:,:,0:512] -> d_out fp32 (b, 512, 1024)
    gemm_k<<<dim3(8, 4, 16), 512, 0, stream>>>(
        yt, 512, 0, wb_cv2, 512, s_cv2, b_cv2,
        nullptr, 0, 0, nullptr, 0, 0, (float*)d_out, nullptr, 1);
}